// Round 3
// baseline (474.838 us; speedup 1.0000x reference)
//
#include <hip/hip_runtime.h>
#include <hip/hip_bf16.h>

#define T_TOK 4096
#define D_DIM 1024
#define H_DIM 2048

typedef __attribute__((ext_vector_type(8))) short short8;
typedef __attribute__((ext_vector_type(8))) unsigned short ushort8;
typedef __attribute__((ext_vector_type(4))) float floatx4;

__device__ __forceinline__ unsigned short f2bf(float f) {
  unsigned int u = __builtin_bit_cast(unsigned int, f);
  return (unsigned short)((u + 0x7fffu + ((u >> 16) & 1u)) >> 16);
}

__device__ __forceinline__ float bf2f(unsigned short s) {
  unsigned int u = ((unsigned int)s) << 16;
  return __builtin_bit_cast(float, u);
}

__device__ __forceinline__ void glds16(const ushort* g, ushort* l) {
  __builtin_amdgcn_global_load_lds(
      (const __attribute__((address_space(1))) unsigned int*)g,
      (__attribute__((address_space(3))) unsigned int*)l, 16, 0, 0);
}

// ---------------- prep: fp32->bf16 of Wg,Wu,sg,su + router (Wd/sd conversion moved into gemm1) ----
// pair space (2 float4 per thread): Wg [0,2097152) Wu [..,4194304) sg [..,4456448) su [..,4718592)
// blocks [0, 18432): cvt ; blocks [18432, 19456): router (4 tokens per block, 1 per wave)
__global__ void prep_kernel(const float4* __restrict__ Wg, ushort4* __restrict__ Wgb,
                            const float4* __restrict__ Wu, ushort4* __restrict__ Wub,
                            const float4* __restrict__ sg, ushort4* __restrict__ sgb,
                            const float4* __restrict__ su, ushort4* __restrict__ sub,
                            const float* __restrict__ x, const float* __restrict__ wr,
                            ushort* __restrict__ xb,
                            int* __restrict__ topi, float2* __restrict__ topw) {
  if (blockIdx.x < 18432) {
    int p = blockIdx.x * 256 + threadIdx.x;  // pair index
    const float4* s; ushort4* d; int pp;
    if (p < 2097152)      { s = Wg; d = Wgb; pp = p; }
    else if (p < 4194304) { s = Wu; d = Wub; pp = p - 2097152; }
    else if (p < 4456448) { s = sg; d = sgb; pp = p - 4194304; }
    else                  { s = su; d = sub; pp = p - 4456448; }
    int i = pp * 2;  // even float4 index
    float4 v0 = s[i];
    float4 v1 = s[i + 1];
    ushort8 o;
    o[0] = f2bf(v0.x); o[1] = f2bf(v0.y); o[2] = f2bf(v0.z); o[3] = f2bf(v0.w);
    o[4] = f2bf(v1.x); o[5] = f2bf(v1.y); o[6] = f2bf(v1.z); o[7] = f2bf(v1.w);
    *(ushort8*)(d + i) = o;  // i even -> 16B aligned
    return;
  }
  // ---- router ----
  const int w = threadIdx.x >> 6;
  const int l = threadIdx.x & 63;
  const int t = (blockIdx.x - 18432) * 4 + w;  // one token per wave
  const float4* xr = (const float4*)(x + (size_t)t * D_DIM);
  ushort4* xo = (ushort4*)(xb + (size_t)t * D_DIM);
  float p[8];
#pragma unroll
  for (int e = 0; e < 8; ++e) p[e] = 0.f;
#pragma unroll
  for (int i = 0; i < 4; ++i) {
    float4 xv = xr[i * 64 + l];
    ushort4 o;
    o.x = f2bf(xv.x); o.y = f2bf(xv.y); o.z = f2bf(xv.z); o.w = f2bf(xv.w);
    xo[i * 64 + l] = o;
#pragma unroll
    for (int e = 0; e < 8; ++e) {
      float4 wv = ((const float4*)(wr + e * D_DIM))[i * 64 + l];
      p[e] += xv.x * wv.x + xv.y * wv.y + xv.z * wv.z + xv.w * wv.w;
    }
  }
#pragma unroll
  for (int off = 32; off > 0; off >>= 1) {
#pragma unroll
    for (int e = 0; e < 8; ++e) p[e] += __shfl_xor(p[e], off, 64);
  }
  if (l == 0) {
    float mx = p[0];
#pragma unroll
    for (int e = 1; e < 8; ++e) mx = fmaxf(mx, p[e]);
    float pr[8];
#pragma unroll
    for (int e = 0; e < 8; ++e) pr[e] = __expf(p[e] - mx);
    int i0 = 0;
#pragma unroll
    for (int e = 1; e < 8; ++e) if (pr[e] > pr[i0]) i0 = e;
    int i1 = (i0 == 0) ? 1 : 0;
#pragma unroll
    for (int e = 0; e < 8; ++e) if (e != i0 && pr[e] > pr[i1]) i1 = e;
    float w0 = pr[i0], w1 = pr[i1];
    float inv = 1.f / (w0 + w1);
    topi[t] = i0 | (i1 << 8);
    topw[t] = make_float2(w0 * inv, w1 * inv);
  }
}

// ---------------- deterministic list build + per-token position map ----------------
__global__ void build_lists_kernel(const int* __restrict__ topi,
                                   int* __restrict__ counts, int* __restrict__ list,
                                   int* __restrict__ pos) {
  const int e = blockIdx.x;
  const int tid = threadIdx.x;
  const int l = tid & 63;
  const int w = tid >> 6;
  __shared__ int wtot[4];
  int base = 0;
  for (int c = 0; c < T_TOK; c += 256) {
    int t = c + tid;
    int ti = topi[t];
    int e0 = ti & 255, e1 = ti >> 8;
    bool flag = (e0 == e) || (e1 == e);
    unsigned long long m = __ballot(flag);
    int lanepos = __popcll(m & ((1ull << l) - 1ull));
    if (l == 0) wtot[w] = __popcll(m);
    __syncthreads();
    int waveoff = 0;
#pragma unroll
    for (int i = 0; i < 4; ++i) waveoff += (i < w) ? wtot[i] : 0;
    int tot = wtot[0] + wtot[1] + wtot[2] + wtot[3];
    if (flag) {
      int p = base + waveoff + lanepos;
      list[e * T_TOK + p] = t;
      int slot = (e0 == e) ? 0 : 1;
      pos[t * 2 + slot] = p;
    }
    base += tot;
    __syncthreads();
  }
  if (tid == 0) counts[e] = base;
}

// ---------------- GEMM1: fused gate+up, SwiGLU epilogue -> h (bf16) ----------------
// 1-D grid of 5120 blocks: every 10th block (h%10==9, 512 blocks) converts Wd+sd fp32->bf16
// (needed only by gemm2, which launches after this grid completes) -- overlaps conversion
// traffic with gemm1's stall slack. Remaining 4608 blocks: g = h-(h+1)/10 decodes to
// (e = g>>9, y = (g&511)>>4, x = g&15) -- identical tiling to the verified round-0 kernel.
__global__ __launch_bounds__(256, 2)
void gemm1_kernel(const ushort* __restrict__ xb,
                  const ushort* __restrict__ Wgb, const ushort* __restrict__ Wub,
                  const ushort* __restrict__ sgb, const ushort* __restrict__ sub,
                  const int* __restrict__ list, const int* __restrict__ counts,
                  ushort* __restrict__ h,
                  const float4* __restrict__ Wd32, ushort4* __restrict__ Wdb,
                  const float4* __restrict__ sd32, ushort4* __restrict__ sdb) {
  const int hlin = blockIdx.x;
  if ((hlin % 10) == 9) {
    // ---- Wd/sd conversion: 512 blocks x 256 threads x 18 pairs ----
    // pair space: Wd [0, 2097152), sd [2097152, 2359296)
    int base = (hlin / 10) * 256 + threadIdx.x;
#pragma unroll
    for (int it = 0; it < 18; ++it) {
      int p = base + it * 131072;
      const float4* s; ushort4* d; int i;
      if (p < 2097152) { s = Wd32; d = Wdb; i = p * 2; }
      else             { s = sd32; d = sdb; i = (p - 2097152) * 2; }
      float4 v0 = s[i];
      float4 v1 = s[i + 1];
      ushort8 o;
      o[0] = f2bf(v0.x); o[1] = f2bf(v0.y); o[2] = f2bf(v0.z); o[3] = f2bf(v0.w);
      o[4] = f2bf(v1.x); o[5] = f2bf(v1.y); o[6] = f2bf(v1.z); o[7] = f2bf(v1.w);
      *(ushort8*)(d + i) = o;
    }
    return;
  }
  const int g = hlin - (hlin + 1) / 10;
  const int e = g >> 9;
  const int rem = g & 511;
  const int by = rem >> 4;
  const int bx = rem & 15;

  int n_e, hbase;
  {
    int acc = 0, ce = 0;
    for (int q = 0; q < 8; ++q) {
      int c = counts[q];
      if (q < e) acc += c;
      if (q == e) ce = c;
    }
    n_e = (e == 8) ? T_TOK : ce;
    hbase = (e == 8) ? 8192 : acc;
  }
  const int r0 = by * 128;
  if (r0 >= n_e) return;
  const int c0 = bx * 128;
  const ushort* Wg = (e == 8) ? sgb : (Wgb + (size_t)e * H_DIM * D_DIM);
  const ushort* Wu = (e == 8) ? sub : (Wub + (size_t)e * H_DIM * D_DIM);
  const int hrow0 = hbase + r0;

  __shared__ __align__(16) ushort As[128 * 64];
  __shared__ __align__(16) ushort Bgs[128 * 64];
  __shared__ __align__(16) ushort Bus[128 * 64];
  __shared__ int toks[128];

  const int tid = threadIdx.x;
  const int l = tid & 63;
  const int w = tid >> 6;

  if (tid < 128) {
    int rr = r0 + tid;
    toks[tid] = (e == 8) ? ((rr < T_TOK) ? rr : (T_TOK - 1))
                         : list[e * T_TOK + ((rr < n_e) ? rr : (n_e - 1))];
  }
  __syncthreads();

  const int lrow8 = l >> 3;
  const int csw = (((l & 7) ^ lrow8) << 3);  // XOR-swizzled k-chunk (element offset)
  const ushort* ap[4];
#pragma unroll
  for (int i = 0; i < 4; ++i) {
    int ri = (w * 4 + i) * 8 + lrow8;
    ap[i] = xb + (size_t)toks[ri] * D_DIM + csw;
  }
  const ushort* bgp = Wg + (size_t)(c0 + w * 32 + lrow8) * D_DIM + csw;
  const ushort* bup = Wu + (size_t)(c0 + w * 32 + lrow8) * D_DIM + csw;

  floatx4 accg[4][4], accu[4][4];
#pragma unroll
  for (int i = 0; i < 4; ++i)
#pragma unroll
    for (int j = 0; j < 4; ++j) {
      accg[i][j] = (floatx4)(0.f);
      accu[i][j] = (floatx4)(0.f);
    }

  const int mrow = (w & 1) * 64;
  const int ncol = (w >> 1) * 64;
  int rba[4], rbb[4];
#pragma unroll
  for (int i = 0; i < 4; ++i) {
    rba[i] = (mrow + 16 * i + (l & 15)) * 64;
    rbb[i] = (ncol + 16 * i + (l & 15)) * 64;
  }

  for (int k0 = 0; k0 < D_DIM; k0 += 64) {
    __syncthreads();
#pragma unroll
    for (int i = 0; i < 4; ++i) {
      glds16(ap[i] + k0,                As  + (w * 4 + i) * 512);
      glds16(bgp + k0 + i * 8 * D_DIM,  Bgs + (w * 4 + i) * 512);
      glds16(bup + k0 + i * 8 * D_DIM,  Bus + (w * 4 + i) * 512);
    }
    __syncthreads();
#pragma unroll
    for (int s = 0; s < 2; ++s) {
      const int pq = ((((s << 2) | (l >> 4)) ^ (l & 7)) << 3);
      short8 a[4], bg[4], bu[4];
#pragma unroll
      for (int i = 0; i < 4; ++i) a[i] = *(const short8*)(As + rba[i] + pq);
#pragma unroll
      for (int j = 0; j < 4; ++j) {
        bg[j] = *(const short8*)(Bgs + rbb[j] + pq);
        bu[j] = *(const short8*)(Bus + rbb[j] + pq);
      }
#pragma unroll
      for (int i = 0; i < 4; ++i)
#pragma unroll
        for (int j = 0; j < 4; ++j) {
          accg[i][j] = __builtin_amdgcn_mfma_f32_16x16x32_bf16(a[i], bg[j], accg[i][j], 0, 0, 0);
          accu[i][j] = __builtin_amdgcn_mfma_f32_16x16x32_bf16(a[i], bu[j], accu[i][j], 0, 0, 0);
        }
    }
  }

#pragma unroll
  for (int i = 0; i < 4; ++i) {
#pragma unroll
    for (int r = 0; r < 4; ++r) {
      int lrow = mrow + 16 * i + (l >> 4) * 4 + r;
      if (r0 + lrow < n_e) {
#pragma unroll
        for (int j = 0; j < 4; ++j) {
          float g2 = accg[i][j][r];
          float u = accu[i][j][r];
          float hv = (g2 / (1.f + __expf(-g2))) * u;
          int col = c0 + ncol + 16 * j + (l & 15);
          h[(size_t)(hrow0 + lrow) * H_DIM + col] = f2bf(hv);
        }
      }
    }
  }
}

// ---------------- GEMM2: down-proj -> eo rows (bf16), 128x128 tile ----------------
// Retiled from 128x256 -> 128x128: ~800 active blocks (was ~384), LDS 32 KB (was 48)
// -> 4-5 blocks/CU co-resident for inter-block latency hiding (the mechanism that makes
// the 2-barrier structure work). grid: x = D col-tile (8), y = row-tile (32), z = expert (9)
__global__ __launch_bounds__(256, 2)
void gemm2_kernel(const ushort* __restrict__ h,
                  const ushort* __restrict__ Wdb, const ushort* __restrict__ sdb,
                  const int* __restrict__ counts,
                  ushort* __restrict__ eo) {
  const int e = blockIdx.z;
  int n_e, hbase;
  {
    int acc0 = 0, ce = 0;
    for (int q = 0; q < 8; ++q) {
      int c = counts[q];
      if (q < e) acc0 += c;
      if (q == e) ce = c;
    }
    n_e = (e == 8) ? T_TOK : ce;
    hbase = (e == 8) ? 8192 : acc0;
  }
  const int r0 = blockIdx.y * 128;
  if (r0 >= n_e) return;
  const int c0 = blockIdx.x * 128;
  const ushort* Wd = (e == 8) ? sdb : (Wdb + (size_t)e * D_DIM * H_DIM);
  const int hrow0 = hbase + r0;

  __shared__ __align__(16) ushort As[128 * 64];
  __shared__ __align__(16) ushort Bs[128 * 64];

  const int tid = threadIdx.x;
  const int l = tid & 63;
  const int w = tid >> 6;

  const int lrow8 = l >> 3;
  const int csw = (((l & 7) ^ lrow8) << 3);
  const ushort* apb = h  + (size_t)(hrow0 + w * 32 + lrow8) * H_DIM + csw;
  const ushort* bpb = Wd + (size_t)(c0 + w * 32 + lrow8) * H_DIM + csw;

  floatx4 acc[4][4];
#pragma unroll
  for (int i = 0; i < 4; ++i)
#pragma unroll
    for (int j = 0; j < 4; ++j) acc[i][j] = (floatx4)(0.f);

  const int mrow = (w & 1) * 64;
  const int ncol = (w >> 1) * 64;
  int rba[4], rbb[4];
#pragma unroll
  for (int i = 0; i < 4; ++i) {
    rba[i] = (mrow + 16 * i + (l & 15)) * 64;
    rbb[i] = (ncol + 16 * i + (l & 15)) * 64;
  }

  for (int k0 = 0; k0 < H_DIM; k0 += 64) {
    __syncthreads();
#pragma unroll
    for (int i = 0; i < 4; ++i) {
      glds16(apb + k0 + i * 8 * H_DIM, As + (w * 4 + i) * 512);
      glds16(bpb + k0 + i * 8 * H_DIM, Bs + (w * 4 + i) * 512);
    }
    __syncthreads();
#pragma unroll
    for (int s = 0; s < 2; ++s) {
      const int pq = ((((s << 2) | (l >> 4)) ^ (l & 7)) << 3);
      short8 a[4], b[4];
#pragma unroll
      for (int i = 0; i < 4; ++i) a[i] = *(const short8*)(As + rba[i] + pq);
#pragma unroll
      for (int j = 0; j < 4; ++j) b[j] = *(const short8*)(Bs + rbb[j] + pq);
#pragma unroll
      for (int i = 0; i < 4; ++i)
#pragma unroll
        for (int j = 0; j < 4; ++j)
          acc[i][j] = __builtin_amdgcn_mfma_f32_16x16x32_bf16(a[i], b[j], acc[i][j], 0, 0, 0);
    }
  }

#pragma unroll
  for (int i = 0; i < 4; ++i) {
#pragma unroll
    for (int r = 0; r < 4; ++r) {
      int lrow = mrow + 16 * i + (l >> 4) * 4 + r;
      if (r0 + lrow < n_e) {
#pragma unroll
        for (int j = 0; j < 4; ++j) {
          int col = c0 + ncol + 16 * j + (l & 15);
          eo[(size_t)(hrow0 + lrow) * D_DIM + col] = f2bf(acc[i][j][r]);
        }
      }
    }
  }
}

// ---------------- combine: out[t] = w0*eo[row(e0)] + w1*eo[row(e1)] + eo[8192+t] ----------------
// 2 tokens per block; 8 cols per thread (16B bf16 loads)
__global__ void combine_kernel(const ushort* __restrict__ eo, const int* __restrict__ topi,
                               const float2* __restrict__ topw, const int* __restrict__ pos,
                               const int* __restrict__ counts, float* __restrict__ out) {
  const int t = blockIdx.x * 2 + (threadIdx.x >> 7);
  const int c = threadIdx.x & 127;  // ushort8 chunk within the row
  int ti = topi[t];
  int e0 = ti & 255, e1 = ti >> 8;
  int off0 = 0, off1 = 0;
#pragma unroll
  for (int q = 0; q < 8; ++q) {
    int cc = counts[q];
    off0 += (q < e0) ? cc : 0;
    off1 += (q < e1) ? cc : 0;
  }
  float2 wv = topw[t];
  int2 p = ((const int2*)pos)[t];
  const short8* ra = (const short8*)(eo + (size_t)(off0 + p.x) * D_DIM);
  const short8* rb = (const short8*)(eo + (size_t)(off1 + p.y) * D_DIM);
  const short8* rs = (const short8*)(eo + (size_t)(8192 + t) * D_DIM);
  short8 a = ra[c], b = rb[c], s = rs[c];
  float o[8];
#pragma unroll
  for (int j = 0; j < 8; ++j)
    o[j] = wv.x * bf2f((unsigned short)a[j]) + wv.y * bf2f((unsigned short)b[j]) +
           bf2f((unsigned short)s[j]);
  float4* op = (float4*)(out + (size_t)t * D_DIM + c * 8);
  op[0] = make_float4(o[0], o[1], o[2], o[3]);
  op[1] = make_float4(o[4], o[5], o[6], o[7]);
}

// ---------------- workspace layout ----------------
#define OFF_XB   0ull
#define OFF_WGB  (OFF_XB + 8388608ull)
#define OFF_WUB  (OFF_WGB + 33554432ull)
#define OFF_WDB  (OFF_WUB + 33554432ull)
#define OFF_SGB  (OFF_WDB + 33554432ull)
#define OFF_SUB  (OFF_SGB + 4194304ull)
#define OFF_SDB  (OFF_SUB + 4194304ull)
#define OFF_H    (OFF_SDB + 4194304ull)
#define OFF_EO   OFF_WGB  /* eo aliases Wgb: Wgb dead after gemm1, eo written by gemm2 */
#define OFF_CNT  (OFF_H + 50331648ull)
#define OFF_LIST (OFF_CNT + 64ull)
#define OFF_POS  (OFF_LIST + 131072ull)
#define OFF_TOPI (OFF_POS + 32768ull)
#define OFF_TOPW (OFF_TOPI + 16384ull)

extern "C" void kernel_launch(void* const* d_in, const int* in_sizes, int n_in,
                              void* d_out, int out_size, void* d_ws, size_t ws_size,
                              hipStream_t stream) {
  const float* x  = (const float*)d_in[0];
  const float* wr = (const float*)d_in[1];
  const float* Wg = (const float*)d_in[2];
  const float* Wu = (const float*)d_in[3];
  const float* Wd = (const float*)d_in[4];
  const float* sg = (const float*)d_in[5];
  const float* su = (const float*)d_in[6];
  const float* sd = (const float*)d_in[7];
  float* out = (float*)d_out;
  char* ws = (char*)d_ws;

  ushort* xb  = (ushort*)(ws + OFF_XB);
  ushort* Wgb = (ushort*)(ws + OFF_WGB);
  ushort* Wub = (ushort*)(ws + OFF_WUB);
  ushort* Wdb = (ushort*)(ws + OFF_WDB);
  ushort* sgb = (ushort*)(ws + OFF_SGB);
  ushort* sub = (ushort*)(ws + OFF_SUB);
  ushort* sdb = (ushort*)(ws + OFF_SDB);
  ushort* hbuf = (ushort*)(ws + OFF_H);
  ushort* eo   = (ushort*)(ws + OFF_EO);
  int* counts = (int*)(ws + OFF_CNT);
  int* list   = (int*)(ws + OFF_LIST);
  int* pos    = (int*)(ws + OFF_POS);
  int* topi   = (int*)(ws + OFF_TOPI);
  float2* topw = (float2*)(ws + OFF_TOPW);

  prep_kernel<<<19456, 256, 0, stream>>>((const float4*)Wg, (ushort4*)Wgb,
                                         (const float4*)Wu, (ushort4*)Wub,
                                         (const float4*)sg, (ushort4*)sgb,
                                         (const float4*)su, (ushort4*)sub,
                                         x, wr, xb, topi, topw);
  build_lists_kernel<<<8, 256, 0, stream>>>(topi, counts, list, pos);

  gemm1_kernel<<<5120, 256, 0, stream>>>(xb, Wgb, Wub, sgb, sub,
                                         list, counts, hbuf,
                                         (const float4*)Wd, (ushort4*)Wdb,
                                         (const float4*)sd, (ushort4*)sdb);
  gemm2_kernel<<<dim3(8, 32, 9), 256, 0, stream>>>(hbuf, Wdb, sdb, counts, eo);
  combine_kernel<<<2048, 256, 0, stream>>>(eo, topi, topw, pos, counts, out);
}

// Round 4
// 434.640 us; speedup vs baseline: 1.0925x; 1.0925x over previous
//
#include <hip/hip_runtime.h>
#include <hip/hip_bf16.h>

#define T_TOK 4096
#define D_DIM 1024
#define H_DIM 2048

typedef __attribute__((ext_vector_type(8))) short short8;
typedef __attribute__((ext_vector_type(8))) unsigned short ushort8;
typedef __attribute__((ext_vector_type(4))) float floatx4;

__device__ __forceinline__ unsigned short f2bf(float f) {
  unsigned int u = __builtin_bit_cast(unsigned int, f);
  return (unsigned short)((u + 0x7fffu + ((u >> 16) & 1u)) >> 16);
}

__device__ __forceinline__ float bf2f(unsigned short s) {
  unsigned int u = ((unsigned int)s) << 16;
  return __builtin_bit_cast(float, u);
}

__device__ __forceinline__ void glds16(const ushort* g, ushort* l) {
  __builtin_amdgcn_global_load_lds(
      (const __attribute__((address_space(1))) unsigned int*)g,
      (__attribute__((address_space(3))) unsigned int*)l, 16, 0, 0);
}

// ---------------- router: x fp32->bf16 + top-2 gating (1024 blocks, 1 token/wave) ----------------
__global__ void router_kernel(const float* __restrict__ x, const float* __restrict__ wr,
                              ushort* __restrict__ xb,
                              int* __restrict__ topi, float2* __restrict__ topw) {
  const int w = threadIdx.x >> 6;
  const int l = threadIdx.x & 63;
  const int t = blockIdx.x * 4 + w;  // one token per wave
  const float4* xr = (const float4*)(x + (size_t)t * D_DIM);
  ushort4* xo = (ushort4*)(xb + (size_t)t * D_DIM);
  float p[8];
#pragma unroll
  for (int e = 0; e < 8; ++e) p[e] = 0.f;
#pragma unroll
  for (int i = 0; i < 4; ++i) {
    float4 xv = xr[i * 64 + l];
    ushort4 o;
    o.x = f2bf(xv.x); o.y = f2bf(xv.y); o.z = f2bf(xv.z); o.w = f2bf(xv.w);
    xo[i * 64 + l] = o;
#pragma unroll
    for (int e = 0; e < 8; ++e) {
      float4 wv = ((const float4*)(wr + e * D_DIM))[i * 64 + l];
      p[e] += xv.x * wv.x + xv.y * wv.y + xv.z * wv.z + xv.w * wv.w;
    }
  }
#pragma unroll
  for (int off = 32; off > 0; off >>= 1) {
#pragma unroll
    for (int e = 0; e < 8; ++e) p[e] += __shfl_xor(p[e], off, 64);
  }
  if (l == 0) {
    float mx = p[0];
#pragma unroll
    for (int e = 1; e < 8; ++e) mx = fmaxf(mx, p[e]);
    float pr[8];
#pragma unroll
    for (int e = 0; e < 8; ++e) pr[e] = __expf(p[e] - mx);
    int i0 = 0;
#pragma unroll
    for (int e = 1; e < 8; ++e) if (pr[e] > pr[i0]) i0 = e;
    int i1 = (i0 == 0) ? 1 : 0;
#pragma unroll
    for (int e = 0; e < 8; ++e) if (e != i0 && pr[e] > pr[i1]) i1 = e;
    float w0 = pr[i0], w1 = pr[i1];
    float inv = 1.f / (w0 + w1);
    topi[t] = i0 | (i1 << 8);
    topw[t] = make_float2(w0 * inv, w1 * inv);
  }
}

// ---------------- cvt+build: blocks 0-7 build expert lists; blocks 8+ convert weights ----------------
// Build (8 blocks, ~25 us latency-bound) hides under the ~60 us streaming conversion.
// cvt flat float4 space 14,155,776:
//   Wg [0, 4194304) Wu [.., 8388608) Wd [.., 12582912) sg [.., 13107200) su [.., 13631488) sd [.., 14155776)
__global__ void cvt_build_kernel(const float4* __restrict__ Wg, ushort4* __restrict__ Wgb,
                                 const float4* __restrict__ Wu, ushort4* __restrict__ Wub,
                                 const float4* __restrict__ Wd, ushort4* __restrict__ Wdb,
                                 const float4* __restrict__ sg, ushort4* __restrict__ sgb,
                                 const float4* __restrict__ su, ushort4* __restrict__ sub,
                                 const float4* __restrict__ sd, ushort4* __restrict__ sdb,
                                 const int* __restrict__ topi,
                                 int* __restrict__ counts, int* __restrict__ list,
                                 int* __restrict__ pos) {
  if (blockIdx.x >= 8) {
    int id = (blockIdx.x - 8) * 256 + threadIdx.x;
    const float4* s; ushort4* d; int i;
    if (id < 4194304)       { s = Wg; d = Wgb; i = id; }
    else if (id < 8388608)  { s = Wu; d = Wub; i = id - 4194304; }
    else if (id < 12582912) { s = Wd; d = Wdb; i = id - 8388608; }
    else if (id < 13107200) { s = sg; d = sgb; i = id - 12582912; }
    else if (id < 13631488) { s = su; d = sub; i = id - 13107200; }
    else                    { s = sd; d = sdb; i = id - 13631488; }
    float4 v = s[i];
    ushort4 o;
    o.x = f2bf(v.x); o.y = f2bf(v.y); o.z = f2bf(v.z); o.w = f2bf(v.w);
    d[i] = o;
    return;
  }
  // ---- build lists (verified deterministic body; expert = blockIdx.x) ----
  const int e = blockIdx.x;
  const int tid = threadIdx.x;
  const int l = tid & 63;
  const int w = tid >> 6;
  __shared__ int wtot[4];
  int base = 0;
  for (int c = 0; c < T_TOK; c += 256) {
    int t = c + tid;
    int ti = topi[t];
    int e0 = ti & 255, e1 = ti >> 8;
    bool flag = (e0 == e) || (e1 == e);
    unsigned long long m = __ballot(flag);
    int lanepos = __popcll(m & ((1ull << l) - 1ull));
    if (l == 0) wtot[w] = __popcll(m);
    __syncthreads();
    int waveoff = 0;
#pragma unroll
    for (int i = 0; i < 4; ++i) waveoff += (i < w) ? wtot[i] : 0;
    int tot = wtot[0] + wtot[1] + wtot[2] + wtot[3];
    if (flag) {
      int p = base + waveoff + lanepos;
      list[e * T_TOK + p] = t;
      int slot = (e0 == e) ? 0 : 1;
      pos[t * 2 + slot] = p;
    }
    base += tot;
    __syncthreads();
  }
  if (tid == 0) counts[e] = base;
}

// ---------------- GEMM1: fused gate+up, SwiGLU epilogue -> h (bf16) ----------------
// BK=64, XOR bank swizzle. grid: x = H col-tile (16), y = row-tile (32), z = expert (9; 8 == shared)
__global__ __launch_bounds__(256, 2)
void gemm1_kernel(const ushort* __restrict__ xb,
                  const ushort* __restrict__ Wgb, const ushort* __restrict__ Wub,
                  const ushort* __restrict__ sgb, const ushort* __restrict__ sub,
                  const int* __restrict__ list, const int* __restrict__ counts,
                  ushort* __restrict__ h) {
  const int e = blockIdx.z;
  int n_e, hbase;
  {
    int acc = 0, ce = 0;
    for (int q = 0; q < 8; ++q) {
      int c = counts[q];
      if (q < e) acc += c;
      if (q == e) ce = c;
    }
    n_e = (e == 8) ? T_TOK : ce;
    hbase = (e == 8) ? 8192 : acc;
  }
  const int r0 = blockIdx.y * 128;
  if (r0 >= n_e) return;
  const int c0 = blockIdx.x * 128;
  const ushort* Wg = (e == 8) ? sgb : (Wgb + (size_t)e * H_DIM * D_DIM);
  const ushort* Wu = (e == 8) ? sub : (Wub + (size_t)e * H_DIM * D_DIM);
  const int hrow0 = hbase + r0;

  __shared__ __align__(16) ushort As[128 * 64];
  __shared__ __align__(16) ushort Bgs[128 * 64];
  __shared__ __align__(16) ushort Bus[128 * 64];
  __shared__ int toks[128];

  const int tid = threadIdx.x;
  const int l = tid & 63;
  const int w = tid >> 6;

  if (tid < 128) {
    int rr = r0 + tid;
    toks[tid] = (e == 8) ? ((rr < T_TOK) ? rr : (T_TOK - 1))
                         : list[e * T_TOK + ((rr < n_e) ? rr : (n_e - 1))];
  }
  __syncthreads();

  const int lrow8 = l >> 3;
  const int csw = (((l & 7) ^ lrow8) << 3);  // XOR-swizzled k-chunk (element offset)
  const ushort* ap[4];
#pragma unroll
  for (int i = 0; i < 4; ++i) {
    int ri = (w * 4 + i) * 8 + lrow8;
    ap[i] = xb + (size_t)toks[ri] * D_DIM + csw;
  }
  const ushort* bgp = Wg + (size_t)(c0 + w * 32 + lrow8) * D_DIM + csw;
  const ushort* bup = Wu + (size_t)(c0 + w * 32 + lrow8) * D_DIM + csw;

  floatx4 accg[4][4], accu[4][4];
#pragma unroll
  for (int i = 0; i < 4; ++i)
#pragma unroll
    for (int j = 0; j < 4; ++j) {
      accg[i][j] = (floatx4)(0.f);
      accu[i][j] = (floatx4)(0.f);
    }

  const int mrow = (w & 1) * 64;
  const int ncol = (w >> 1) * 64;
  int rba[4], rbb[4];
#pragma unroll
  for (int i = 0; i < 4; ++i) {
    rba[i] = (mrow + 16 * i + (l & 15)) * 64;
    rbb[i] = (ncol + 16 * i + (l & 15)) * 64;
  }

  for (int k0 = 0; k0 < D_DIM; k0 += 64) {
    __syncthreads();
#pragma unroll
    for (int i = 0; i < 4; ++i) {
      glds16(ap[i] + k0,                As  + (w * 4 + i) * 512);
      glds16(bgp + k0 + i * 8 * D_DIM,  Bgs + (w * 4 + i) * 512);
      glds16(bup + k0 + i * 8 * D_DIM,  Bus + (w * 4 + i) * 512);
    }
    __syncthreads();
#pragma unroll
    for (int s = 0; s < 2; ++s) {
      const int pq = ((((s << 2) | (l >> 4)) ^ (l & 7)) << 3);
      short8 a[4], bg[4], bu[4];
#pragma unroll
      for (int i = 0; i < 4; ++i) a[i] = *(const short8*)(As + rba[i] + pq);
#pragma unroll
      for (int j = 0; j < 4; ++j) {
        bg[j] = *(const short8*)(Bgs + rbb[j] + pq);
        bu[j] = *(const short8*)(Bus + rbb[j] + pq);
      }
#pragma unroll
      for (int i = 0; i < 4; ++i)
#pragma unroll
        for (int j = 0; j < 4; ++j) {
          accg[i][j] = __builtin_amdgcn_mfma_f32_16x16x32_bf16(a[i], bg[j], accg[i][j], 0, 0, 0);
          accu[i][j] = __builtin_amdgcn_mfma_f32_16x16x32_bf16(a[i], bu[j], accu[i][j], 0, 0, 0);
        }
    }
  }

#pragma unroll
  for (int i = 0; i < 4; ++i) {
#pragma unroll
    for (int r = 0; r < 4; ++r) {
      int lrow = mrow + 16 * i + (l >> 4) * 4 + r;
      if (r0 + lrow < n_e) {
#pragma unroll
        for (int j = 0; j < 4; ++j) {
          float g = accg[i][j][r];
          float u = accu[i][j][r];
          float hv = (g / (1.f + __expf(-g))) * u;
          int col = c0 + ncol + 16 * j + (l & 15);
          h[(size_t)(hrow0 + lrow) * H_DIM + col] = f2bf(hv);
        }
      }
    }
  }
}

// ---------------- GEMM2: down-proj -> eo rows (bf16), 128x256 tile ----------------
// grid: x = D col-tile (4, 256 wide), y = row-tile (32), z = expert (9)
__global__ __launch_bounds__(256, 2)
void gemm2_kernel(const ushort* __restrict__ h,
                  const ushort* __restrict__ Wdb, const ushort* __restrict__ sdb,
                  const int* __restrict__ counts,
                  ushort* __restrict__ eo) {
  const int e = blockIdx.z;
  int n_e, hbase;
  {
    int acc = 0, ce = 0;
    for (int q = 0; q < 8; ++q) {
      int c = counts[q];
      if (q < e) acc += c;
      if (q == e) ce = c;
    }
    n_e = (e == 8) ? T_TOK : ce;
    hbase = (e == 8) ? 8192 : acc;
  }
  const int r0 = blockIdx.y * 128;
  if (r0 >= n_e) return;
  const int c0 = blockIdx.x * 256;
  const ushort* Wd = (e == 8) ? sdb : (Wdb + (size_t)e * D_DIM * H_DIM);
  const int hrow0 = hbase + r0;

  __shared__ __align__(16) ushort As[128 * 64];
  __shared__ __align__(16) ushort Bs[256 * 64];

  const int tid = threadIdx.x;
  const int l = tid & 63;
  const int w = tid >> 6;

  const int lrow8 = l >> 3;
  const int csw = (((l & 7) ^ lrow8) << 3);
  const ushort* apb = h  + (size_t)(hrow0 + w * 32 + lrow8) * H_DIM + csw;
  const ushort* bpb = Wd + (size_t)(c0 + w * 64 + lrow8) * H_DIM + csw;

  floatx4 acc[4][8];
#pragma unroll
  for (int i = 0; i < 4; ++i)
#pragma unroll
    for (int j = 0; j < 8; ++j) acc[i][j] = (floatx4)(0.f);

  const int mrow = (w & 1) * 64;
  const int ncol = (w >> 1) * 128;
  int rba[4], rbb[8];
#pragma unroll
  for (int i = 0; i < 4; ++i) rba[i] = (mrow + 16 * i + (l & 15)) * 64;
#pragma unroll
  for (int j = 0; j < 8; ++j) rbb[j] = (ncol + 16 * j + (l & 15)) * 64;

  for (int k0 = 0; k0 < H_DIM; k0 += 64) {
    __syncthreads();
#pragma unroll
    for (int i = 0; i < 4; ++i)
      glds16(apb + k0 + i * 8 * H_DIM, As + (w * 4 + i) * 512);
#pragma unroll
    for (int i = 0; i < 8; ++i)
      glds16(bpb + k0 + i * 8 * H_DIM, Bs + (w * 8 + i) * 512);
    __syncthreads();
#pragma unroll
    for (int s = 0; s < 2; ++s) {
      const int pq = ((((s << 2) | (l >> 4)) ^ (l & 7)) << 3);
      short8 a[4], b[8];
#pragma unroll
      for (int i = 0; i < 4; ++i) a[i] = *(const short8*)(As + rba[i] + pq);
#pragma unroll
      for (int j = 0; j < 8; ++j) b[j] = *(const short8*)(Bs + rbb[j] + pq);
#pragma unroll
      for (int i = 0; i < 4; ++i)
#pragma unroll
        for (int j = 0; j < 8; ++j)
          acc[i][j] = __builtin_amdgcn_mfma_f32_16x16x32_bf16(a[i], b[j], acc[i][j], 0, 0, 0);
    }
  }

#pragma unroll
  for (int i = 0; i < 4; ++i) {
#pragma unroll
    for (int r = 0; r < 4; ++r) {
      int lrow = mrow + 16 * i + (l >> 4) * 4 + r;
      if (r0 + lrow < n_e) {
#pragma unroll
        for (int j = 0; j < 8; ++j) {
          int col = c0 + ncol + 16 * j + (l & 15);
          eo[(size_t)(hrow0 + lrow) * D_DIM + col] = f2bf(acc[i][j][r]);
        }
      }
    }
  }
}

// ---------------- combine: out[t] = w0*eo[row(e0)] + w1*eo[row(e1)] + eo[8192+t] ----------------
// 2 tokens per block; 8 cols per thread (16B bf16 loads)
__global__ void combine_kernel(const ushort* __restrict__ eo, const int* __restrict__ topi,
                               const float2* __restrict__ topw, const int* __restrict__ pos,
                               const int* __restrict__ counts, float* __restrict__ out) {
  const int t = blockIdx.x * 2 + (threadIdx.x >> 7);
  const int c = threadIdx.x & 127;  // ushort8 chunk within the row
  int ti = topi[t];
  int e0 = ti & 255, e1 = ti >> 8;
  int off0 = 0, off1 = 0;
#pragma unroll
  for (int q = 0; q < 8; ++q) {
    int cc = counts[q];
    off0 += (q < e0) ? cc : 0;
    off1 += (q < e1) ? cc : 0;
  }
  float2 wv = topw[t];
  int2 p = ((const int2*)pos)[t];
  const short8* ra = (const short8*)(eo + (size_t)(off0 + p.x) * D_DIM);
  const short8* rb = (const short8*)(eo + (size_t)(off1 + p.y) * D_DIM);
  const short8* rs = (const short8*)(eo + (size_t)(8192 + t) * D_DIM);
  short8 a = ra[c], b = rb[c], s = rs[c];
  float o[8];
#pragma unroll
  for (int j = 0; j < 8; ++j)
    o[j] = wv.x * bf2f((unsigned short)a[j]) + wv.y * bf2f((unsigned short)b[j]) +
           bf2f((unsigned short)s[j]);
  float4* op = (float4*)(out + (size_t)t * D_DIM + c * 8);
  op[0] = make_float4(o[0], o[1], o[2], o[3]);
  op[1] = make_float4(o[4], o[5], o[6], o[7]);
}

// ---------------- workspace layout ----------------
#define OFF_XB   0ull
#define OFF_WGB  (OFF_XB + 8388608ull)
#define OFF_WUB  (OFF_WGB + 33554432ull)
#define OFF_WDB  (OFF_WUB + 33554432ull)
#define OFF_SGB  (OFF_WDB + 33554432ull)
#define OFF_SUB  (OFF_SGB + 4194304ull)
#define OFF_SDB  (OFF_SUB + 4194304ull)
#define OFF_H    (OFF_SDB + 4194304ull)
#define OFF_EO   OFF_WGB  /* eo aliases Wgb: Wgb dead after gemm1, eo written by gemm2 */
#define OFF_CNT  (OFF_H + 50331648ull)
#define OFF_LIST (OFF_CNT + 64ull)
#define OFF_POS  (OFF_LIST + 131072ull)
#define OFF_TOPI (OFF_POS + 32768ull)
#define OFF_TOPW (OFF_TOPI + 16384ull)

extern "C" void kernel_launch(void* const* d_in, const int* in_sizes, int n_in,
                              void* d_out, int out_size, void* d_ws, size_t ws_size,
                              hipStream_t stream) {
  const float* x  = (const float*)d_in[0];
  const float* wr = (const float*)d_in[1];
  const float* Wg = (const float*)d_in[2];
  const float* Wu = (const float*)d_in[3];
  const float* Wd = (const float*)d_in[4];
  const float* sg = (const float*)d_in[5];
  const float* su = (const float*)d_in[6];
  const float* sd = (const float*)d_in[7];
  float* out = (float*)d_out;
  char* ws = (char*)d_ws;

  ushort* xb  = (ushort*)(ws + OFF_XB);
  ushort* Wgb = (ushort*)(ws + OFF_WGB);
  ushort* Wub = (ushort*)(ws + OFF_WUB);
  ushort* Wdb = (ushort*)(ws + OFF_WDB);
  ushort* sgb = (ushort*)(ws + OFF_SGB);
  ushort* sub = (ushort*)(ws + OFF_SUB);
  ushort* sdb = (ushort*)(ws + OFF_SDB);
  ushort* hbuf = (ushort*)(ws + OFF_H);
  ushort* eo   = (ushort*)(ws + OFF_EO);
  int* counts = (int*)(ws + OFF_CNT);
  int* list   = (int*)(ws + OFF_LIST);
  int* pos    = (int*)(ws + OFF_POS);
  int* topi   = (int*)(ws + OFF_TOPI);
  float2* topw = (float2*)(ws + OFF_TOPW);

  router_kernel<<<1024, 256, 0, stream>>>(x, wr, xb, topi, topw);
  cvt_build_kernel<<<55304, 256, 0, stream>>>((const float4*)Wg, (ushort4*)Wgb,
                                              (const float4*)Wu, (ushort4*)Wub,
                                              (const float4*)Wd, (ushort4*)Wdb,
                                              (const float4*)sg, (ushort4*)sgb,
                                              (const float4*)su, (ushort4*)sub,
                                              (const float4*)sd, (ushort4*)sdb,
                                              topi, counts, list, pos);

  gemm1_kernel<<<dim3(16, 32, 9), 256, 0, stream>>>(xb, Wgb, Wub, sgb, sub,
                                                    list, counts, hbuf);
  gemm2_kernel<<<dim3(4, 32, 9), 256, 0, stream>>>(hbuf, Wdb, sdb, counts, eo);
  combine_kernel<<<2048, 256, 0, stream>>>(eo, topi, topw, pos, counts, out);
}